// Round 7
// baseline (115.481 us; speedup 1.0000x reference)
//
#include <hip/hip_runtime.h>
#include <hip/hip_bf16.h>

// CARAFE fused: B=4, C=128, H=W=64, C_MID=64, S=2, K=5
// Round 17: r16 + three fixes:
//  (1) phase E -> LDS-staged, 16B-coalesced float4 writeback (4 batches)
//  (2) phase C 9-deep B-operand prefetch (amortize L2 latency 9x)
//  (3) no-alias LDS (80,640 B, still 2 blocks/CU): D1 zero-phase + barrier gone,
//      W zeroed during phase A.
#define HW 4096
#define XSTR 100

typedef __attribute__((ext_vector_type(8))) short  short8;   // 8 bf16 (4 VGPRs)
typedef __attribute__((ext_vector_type(4))) float  floatx4;  // MFMA C/D
typedef __attribute__((ext_vector_type(4))) unsigned short ushort4v;

// workspace (BYTE offsets)
#define OFF_W2B 0ul        // bf16 [112][576]  = 129024 B   w2b[n][k], k = tap*64 + c
#define OFF_W1B 129024ul   // bf16 [64][128]   = 16384 B    w1b[o][c]
#define OFF_BN  145408ul   // float2[64]       = 512 B      (inv, add) per o
#define OFF_XG  145920ul   // bf16 [4][16][4096][8] = 4 MB  x transposed: [b][cq][pix][8c]
#define OFF_XPP 4340224ul  // bf16 [512][68][68]    = 4.73 MB zero-padded planar x

// ---------------- prep (r12 verbatim) ----------------
__global__ __launch_bounds__(256) void prep_kernel(const float* __restrict__ x,
                                                   const float* __restrict__ w1,
                                                   const float* __restrict__ w2,
                                                   const float* __restrict__ gamma,
                                                   const float* __restrict__ beta,
                                                   const float* __restrict__ mean,
                                                   const float* __restrict__ var,
                                                   char* __restrict__ ws) {
    int tid = blockIdx.x * 256 + threadIdx.x;
    if (tid < 262144) {
        int pix = tid & 4095;
        int cq  = (tid >> 12) & 15;
        int b   = tid >> 16;
        const float* xp = x + ((size_t)(b * 128 + cq * 8)) * HW + pix;
        union { short8 s; __hip_bfloat16 h[8]; } u;
        #pragma unroll
        for (int cc = 0; cc < 8; ++cc) u.h[cc] = __float2bfloat16(xp[(size_t)cc * HW]);
        *(short8*)((__hip_bfloat16*)(ws + OFF_XG) + (size_t)tid * 8) = u.s;
        return;
    }
    int t2 = tid - 262144;
    if (t2 < 64512) {
        int n = t2 / 576;
        int k = t2 - n * 576;        // k = tap*64 + c
        int t = k >> 6, c = k & 63;
        float v = (n < 100) ? w2[(n * 64 + c) * 9 + t] : 0.f;
        ((__hip_bfloat16*)(ws + OFF_W2B))[t2] = __float2bfloat16(v);
    } else if (t2 < 64512 + 8192) {
        int i = t2 - 64512;
        ((__hip_bfloat16*)(ws + OFF_W1B))[i] = __float2bfloat16(w1[i]);
    } else if (t2 < 64512 + 8192 + 64) {
        int o = t2 - 64512 - 8192;
        float inv = gamma[o] * rsqrtf(var[o] + 1e-5f);
        ((float2*)(ws + OFF_BN))[o] = make_float2(inv, beta[o] - mean[o] * inv);
    } else {
        int t3 = t2 - 72768;          // XPP: zero-padded planar bf16 copy
        if (t3 < 591872) {            // 512 bc * 68 rows * 17 chunks
            int j  = t3 % 17;
            int rr = t3 / 17;         // (b*128+c)*68 + row68
            int row68 = rr - (rr / 68) * 68;
            int bc = rr / 68;
            int gy = row68 - 2;
            const float* xp = x + (size_t)bc * HW + (size_t)gy * 64;
            union { ushort4v u4; __hip_bfloat16 h[4]; } u;
            #pragma unroll
            for (int e = 0; e < 4; ++e) {
                int gx = j * 4 + e - 2;
                float f = 0.f;
                if ((unsigned)gy < 64u && (unsigned)gx < 64u) f = xp[gx];
                u.h[e] = __float2bfloat16(f);
            }
            *(ushort4v*)((__hip_bfloat16*)(ws + OFF_XPP) + (size_t)rr * 68 + j * 4) = u.u4;
        }
    }
}

// ---------------- fused CARAFE: one block per (b, 4x8 tile), 512 threads = 8 waves ----------
// LDS (80,640 B, NO aliasing):
//   xsT [128 c][8 r][12 col] bf16, row-stride 100  @ 0      (25,600)  live A..E
//   lg  [32 pix][114] f32                          @ 25600  (14,592)  live C..D
//   Dst [128 plane][4 rowsel][8 col] f32 staging   @ 25600  (16,384)  live E (lg/hs dead)
//   hs  [60 rows][64 c] bf16 swz                   @ 40192  ( 7,680)  live B..C
//   W   [2 sub][hi/lo][64][64] bf16 swz            @ 47872  (32,768)  zeroed in A, live D2..E
__global__ __launch_bounds__(512, 4) void fused_carafe(const char* __restrict__ ws,
                                                       float* __restrict__ out) {
    __shared__ __align__(16) char smem[80640];
    __hip_bfloat16* xsT = (__hip_bfloat16*)smem;
    float*          lg  = (float*)(smem + 25600);
    float*          Dst = (float*)(smem + 25600);
    __hip_bfloat16* hs  = (__hip_bfloat16*)(smem + 40192);
    __hip_bfloat16* whp = (__hip_bfloat16*)(smem + 47872);   // [s*8192 + (hi:0/lo:4096) + row*64]

    int b    = blockIdx.x >> 7;
    int tile = blockIdx.x & 127;
    int ty0 = (tile >> 3) * 4;      // 16 tile-rows
    int tx0 = (tile & 7) * 8;       // 8 tile-cols
    int tid = threadIdx.x;
    int lane = tid & 63, wave = tid >> 6;   // 8 waves
    int q = lane >> 4, m = lane & 15;

    // ---- phase A: stage xsT[c][row][col] (8x12 halo) from padded planar XPP ----
    {
        const __hip_bfloat16* xpp = (const __hip_bfloat16*)(ws + OFF_XPP);
        #pragma unroll
        for (int it = 0; it < 2; ++it) {
            int idx = tid + it * 512;             // 1024 = 128 c * 8 rows
            int c = idx >> 3, row = idx & 7;
            const __hip_bfloat16* src = xpp + (size_t)(b * 128 + c) * 4624
                                      + (size_t)(ty0 + row) * 68 + tx0;
            uint2 d0 = *(const uint2*)(src);
            uint2 d1 = *(const uint2*)(src + 4);
            uint2 d2 = *(const uint2*)(src + 8);
            __hip_bfloat16* dst = xsT + c * XSTR + row * 12;
            *(uint2*)(dst)     = d0;
            *(uint2*)(dst + 4) = d1;
            *(uint2*)(dst + 8) = d2;
        }
        // zero W (hi+lo, both subtiles): 32768 B / 512 thr = 64 B each
        short8 z;
        #pragma unroll
        for (int j = 0; j < 8; ++j) z[j] = 0;
        char* wb = (char*)whp + tid * 64;
        #pragma unroll
        for (int j = 0; j < 4; ++j) *(short8*)(wb + j * 16) = z;
    }

    // ---- phase B: h = relu(bn(w1 @ x)); M=60 halo pix (6x10), N=64, K=128 ----
    {
        const __hip_bfloat16* xg  = (const __hip_bfloat16*)(ws + OFF_XG) + (size_t)b * 16 * 4096 * 8;
        const __hip_bfloat16* w1b = (const __hip_bfloat16*)(ws + OFF_W1B);
        #pragma unroll
        for (int rep = 0; rep < 2; ++rep) {
            int task = wave + rep * 8;
            int mt = task >> 2, nt = task & 3;
            int bo = nt * 16 + m;
            float2 bnia = ((const float2*)(ws + OFF_BN))[bo];
            int hp = mt * 16 + m;
            int hpc = (hp < 60) ? hp : 0;          // clamp dead A-rows
            int hy1 = hpc / 10, hx1 = hpc - hy1 * 10;
            int gy = ty0 + hy1 - 1, gx = tx0 + hx1 - 1;
            int gyc = min(max(gy, 0), 63), gxc = min(max(gx, 0), 63);
            int pix = gyc * 64 + gxc;
            floatx4 acc;
            #pragma unroll
            for (int r = 0; r < 4; ++r) acc[r] = 0.f;
            #pragma unroll
            for (int s = 0; s < 4; ++s) {
                short8 a  = *(const short8*)(xg + ((size_t)((s * 4 + q) * 4096 + pix)) * 8);
                short8 bw = *(const short8*)(w1b + bo * 128 + s * 32 + q * 8);
                acc = __builtin_amdgcn_mfma_f32_16x16x32_bf16(a, bw, acc, 0, 0, 0);
            }
            #pragma unroll
            for (int r = 0; r < 4; ++r) {
                int prow = mt * 16 + q * 4 + r;
                if (prow < 60) {
                    int phy = prow / 10, phx = prow - phy * 10;
                    int gy2 = ty0 + phy - 1, gx2 = tx0 + phx - 1;
                    bool in = ((unsigned)gy2 < 64u) && ((unsigned)gx2 < 64u);
                    float v = in ? fmaxf(fmaf(acc[r], bnia.x, bnia.y), 0.f) : 0.f;
                    hs[prow * 64 + ((((bo >> 3) ^ (prow & 7)) << 3) | (bo & 7))] = __float2bfloat16(v);
                }
            }
        }
    }
    __syncthreads();

    // ---- phase C: 3x3 conv via MFMA: M=32 pix, N=112, K=576; 14 tasks; 9-deep prefetch ----
    {
        const __hip_bfloat16* w2b = (const __hip_bfloat16*)(ws + OFF_W2B);
        for (int task = wave; task < 14; task += 8) {
            int mt = task & 1, nt = task >> 1;
            int pixidx = mt * 16 + m;
            int py = pixidx >> 3, px = pixidx & 7;
            const __hip_bfloat16* bp = w2b + (size_t)(nt * 16 + m) * 576 + q * 8;

            short8 bv[9];
            #pragma unroll
            for (int s = 0; s < 9; ++s) bv[s] = *(const short8*)(bp + s * 32);

            floatx4 acc;
            #pragma unroll
            for (int r = 0; r < 4; ++r) acc[r] = 0.f;

            #pragma unroll
            for (int s = 0; s < 18; ++s) {
                int t = s >> 1, co = (s & 1) * 4 + q;      // c-oct index 0..7
                int ti = t / 3, tj = t - ti * 3;
                int row = (py + ti) * 10 + (px + tj);
                short8 a = *(const short8*)(hs + row * 64 + ((co ^ (row & 7)) << 3));
                acc = __builtin_amdgcn_mfma_f32_16x16x32_bf16(a, bv[s % 9], acc, 0, 0, 0);
                if (s < 9) bv[s] = *(const short8*)(bp + (s + 9) * 32);
            }
            #pragma unroll
            for (int r = 0; r < 4; ++r)
                lg[(mt * 16 + q * 4 + r) * 114 + nt * 16 + m] = acc[r];
        }
    }
    __syncthreads();

    // ---- phase D2: wave-parallel softmax (128 rows x 4 subs) -> scatter W hi/lo ----
    {
        int row = tid >> 2, sub = tid & 3;                 // row = pixg 0..127
        int pixid = row >> 2, g = row & 3;
        int py = pixid >> 3, px = pixid & 7;
        int s = px >> 2, pxl = px & 3;
        int wrow = ((py << 2) | pxl) * 4 + g;              // row in subtile-W
        float v[7];
        float mx = -1e30f;
        #pragma unroll
        for (int k = 0; k < 7; ++k) {
            int t25 = sub + k * 4;
            v[k] = (t25 < 25) ? lg[pixid * 114 + g * 25 + t25] : -1e30f;
            mx = fmaxf(mx, v[k]);
        }
        mx = fmaxf(mx, __shfl_xor(mx, 1, 64));
        mx = fmaxf(mx, __shfl_xor(mx, 2, 64));
        float ssum = 0.f;
        #pragma unroll
        for (int k = 0; k < 7; ++k) {
            int t25 = sub + k * 4;
            v[k] = (t25 < 25) ? __expf(v[k] - mx) : 0.f;
            ssum += v[k];
        }
        ssum += __shfl_xor(ssum, 1, 64);
        ssum += __shfl_xor(ssum, 2, 64);
        float rs = 1.f / ssum;
        #pragma unroll
        for (int k = 0; k < 7; ++k) {
            int t25 = sub + k * 4;
            if (t25 < 25) {
                int ti = t25 / 5, tj = t25 - ti * 5;
                int base = s * 8192 + wrow * 64
                         + ((((py + ti) ^ (wrow & 7)) << 3) | (pxl + tj));
                float kv = v[k] * rs;
                __hip_bfloat16 khi = __float2bfloat16(kv);
                whp[base] = khi;
                whp[base + 4096] = __float2bfloat16(kv - __bfloat162float(khi));
            }
        }
    }
    __syncthreads();

    // ---- phase E: out^T per 4x4 subtile, LDS-staged, 16B-coalesced writeback ----
    // batch bb = (s, ptpair): 8 waves = (ch, ptloc, cthalf); each wave 2 ct.
    #pragma unroll
    for (int bb = 0; bb < 4; ++bb) {
        const int s = bb >> 1, ptpair = bb & 1;
        {
            int ch = wave >> 2, ptloc = (wave >> 1) & 1, cthalf = wave & 1;
            int pt = ptpair * 2 + ptloc;
            const __hip_bfloat16* wbase = whp + s * 8192;
            int wrow = pt * 16 + m;
            int s0 = ((q ^ (wrow & 7)) << 3);
            int s1 = (((4 + q) ^ (wrow & 7)) << 3);
            short8 bh0 = *(const short8*)(wbase + wrow * 64 + s0);
            short8 bl0 = *(const short8*)(wbase + 4096 + wrow * 64 + s0);
            short8 bh1 = *(const short8*)(wbase + wrow * 64 + s1);
            short8 bl1 = *(const short8*)(wbase + 4096 + wrow * 64 + s1);
            int pxm = m >> 2, gy = (m >> 1) & 1, gx = m & 1;
            int rowsel = ptloc * 2 + gy;
            int dcol = 2 * pxm + gx;
            #pragma unroll
            for (int ct2 = 0; ct2 < 2; ++ct2) {
                int ct = cthalf * 2 + ct2;
                int ca = ch * 64 + ct * 16 + m;
                const __hip_bfloat16* xr = xsT + ca * XSTR + s * 4;
                union { short8 v; uint2 d[2]; } a0u, a1u;
                a0u.d[0] = *(const uint2*)(xr + q * 12);
                a0u.d[1] = *(const uint2*)(xr + q * 12 + 4);
                a1u.d[0] = *(const uint2*)(xr + (4 + q) * 12);
                a1u.d[1] = *(const uint2*)(xr + (4 + q) * 12 + 4);
                floatx4 acc;
                #pragma unroll
                for (int r = 0; r < 4; ++r) acc[r] = 0.f;
                acc = __builtin_amdgcn_mfma_f32_16x16x32_bf16(a0u.v, bh0, acc, 0, 0, 0);
                acc = __builtin_amdgcn_mfma_f32_16x16x32_bf16(a0u.v, bl0, acc, 0, 0, 0);
                acc = __builtin_amdgcn_mfma_f32_16x16x32_bf16(a1u.v, bh1, acc, 0, 0, 0);
                acc = __builtin_amdgcn_mfma_f32_16x16x32_bf16(a1u.v, bl1, acc, 0, 0, 0);
                int pbase = ch * 64 + ct * 16 + q * 4;
                #pragma unroll
                for (int r = 0; r < 4; ++r)
                    Dst[(pbase + r) * 32 + rowsel * 8 + dcol] = acc[r];
            }
        }
        __syncthreads();
        // writeback: 1024 float4 units; thread -> 2 units, 16B global stores
        {
            #pragma unroll
            for (int i = 0; i < 2; ++i) {
                int unit = tid * 2 + i;
                int plane = unit >> 3, rem = unit & 7;
                int rowsel2 = rem >> 1, q4 = rem & 1;
                const float* sp = Dst + plane * 32 + rowsel2 * 8 + q4 * 4;
                float4 v = *(const float4*)sp;
                int orow = 2 * (ty0 + ptpair * 2 + (rowsel2 >> 1)) + (rowsel2 & 1);
                int ocol = 2 * (tx0 + s * 4) + q4 * 4;
                *(float4*)(out + (((size_t)(b * 128 + plane)) << 14)
                               + (size_t)orow * 128 + ocol) = v;
            }
        }
        if (bb < 3) __syncthreads();
    }
}

extern "C" void kernel_launch(void* const* d_in, const int* in_sizes, int n_in,
                              void* d_out, int out_size, void* d_ws, size_t ws_size,
                              hipStream_t stream) {
    const float* x     = (const float*)d_in[0];
    const float* w1    = (const float*)d_in[1];
    const float* w2    = (const float*)d_in[2];
    const float* gamma = (const float*)d_in[3];
    const float* beta  = (const float*)d_in[4];
    const float* mean  = (const float*)d_in[5];
    const float* var   = (const float*)d_in[6];
    float* out = (float*)d_out;
    char*  ws  = (char*)d_ws;

    prep_kernel<<<3621, 256, 0, stream>>>(x, w1, w2, gamma, beta, mean, var, ws);
    fused_carafe<<<512, 512, 0, stream>>>(ws, out);
}